// Round 11
// baseline (230.623 us; speedup 1.0000x reference)
//
#include <hip/hip_runtime.h>
#include <cstdint>

#define HW 4096
#define NBLK 512

typedef __attribute__((ext_vector_type(8))) short bf16x8;
typedef __attribute__((ext_vector_type(4))) float f32x4;

__device__ __forceinline__ short f2bf(float f) {
    union { float f; uint32_t u; } v; v.f = f;
    uint32_t u = v.u;
    uint32_t r = (u + 0x7FFFu + ((u >> 16) & 1u)) >> 16;
    return (short)(r & 0xFFFFu);
}
__device__ __forceinline__ uint32_t cvtpk(float lo, float hi) {
    uint32_t r;
    asm("v_cvt_pk_bf16_f32 %0, %1, %2" : "=v"(r) : "v"(lo), "v"(hi));
    return r;
}
__device__ __forceinline__ float blo(uint32_t u) { return __uint_as_float(u << 16); }
__device__ __forceinline__ float bhi(uint32_t u) { return __uint_as_float(u & 0xFFFF0000u); }
__device__ __forceinline__ void glds16(const void* g, void* l) {
    __builtin_amdgcn_global_load_lds(
        (const __attribute__((address_space(1))) void*)g,
        (__attribute__((address_space(3))) void*)l, 16, 0, 0);
}

// ---------------------------------------------------------------------------
// SINGLE KERNEL: pre (transpose + weight conv) -> grid barrier -> om GEMM
// (A staged via glds16 LDS double-buffer, 16 KB/iter unique instead of 64 KB
// register-redundant) -> plan -> main fused sampling GEMM (R10 structure).
//
// Grid 512 x 512thr; 2 blocks/CU (LDS 74 KB) -> all 512 blocks co-resident
// (256 CU x 2 = 512 exactly), so the software grid barrier cannot deadlock.
// Barrier: per-thread __threadfence (agent release of xT/a2r/wTb2 writes),
// t0 atomicAdd + acquire spin (invalidates L1/L2 per gfx94x memory model).
// Counter zeroed by a captured hipMemsetAsync before the kernel each replay.
// ---------------------------------------------------------------------------
__global__ __launch_bounds__(512, 4) void k_all(
    const float* __restrict__ x, const float* __restrict__ weight,
    const float* __restrict__ w_off, const float* __restrict__ b_off,
    const float* __restrict__ bias, unsigned short* __restrict__ xT,
    short* __restrict__ a2r, short* __restrict__ wTb2,
    unsigned int* __restrict__ cnt, float* __restrict__ out)
{
    __shared__ short Bs[2][4][32 * 32];    // 16 KB (om B staging + main B)
    __shared__ short AsOm[2][8192];        // 32 KB (om A dbuf; pre aliases it)
    __shared__ float omS[64][32];          //  8 KB
    __shared__ float4 PlnW[18][32];        //  9 KB
    __shared__ int4   PlnI[18][32];        //  9 KB   total ~74 KB -> 2/CU

    const int t = threadIdx.x;
    const int wid = __builtin_amdgcn_readfirstlane(t >> 6);  // 0..7
    const int lane = t & 63;
    const int quad = lane >> 4, l16 = lane & 15;
    const int lin = blockIdx.x;

    // ---------------- Phase 0: preprocessing (was k_pre) ----------------
    {
        unsigned short (*trS)[65] = (unsigned short (*)[65])(&AsOm[0][0]);
        const int grp = t >> 6, ln = t & 63;
#pragma unroll
        for (int k = 0; k < 2; ++k) {
            const int tid = lin * 2 + k;           // 0..1023 transpose tiles
            const int hw0 = (tid & 63) * 64, c0 = ((tid >> 6) & 3) * 64;
            const int bb = tid >> 8;
#pragma unroll
            for (int j = 0; j < 8; ++j) {
                int cc2 = grp * 8 + j;
                trS[cc2][ln] = (unsigned short)f2bf(
                    x[((size_t)(bb * 256 + c0 + cc2)) * HW + hw0 + ln]);
            }
            __syncthreads();
#pragma unroll
            for (int j = 0; j < 8; ++j) {
                int hw2 = grp * 8 + j;
                xT[((size_t)bb * HW + hw0 + hw2) * 256 + c0 + ln] = trS[ln][hw2];
            }
            __syncthreads();
        }
#pragma unroll
        for (int q = 0; q < 3; ++q) {
            int r = q * 512 + t;
            if (r < 1440) {
                int e = lin * 1440 + r;            // 512*1440 = 737280 exact
                if (e < 589824) {
                    int el = e & 7;
                    int ln2 = (e >> 3) & 63;
                    int rg = (e >> 9) & 15;
                    int ss = (e >> 13) & 3;
                    int j = e >> 15;
                    int o = rg * 16 + (ln2 & 15);
                    int cch = ss * 32 + (ln2 >> 4) * 8 + el;
                    int dg = j / 9, tap = j - dg * 9;
                    a2r[e] = f2bf(weight[o * 2304 + (dg * 128 + cch) * 9 + tap]);
                } else {
                    int e2 = e - 589824;
                    int el = e2 & 7;
                    int ln2 = (e2 >> 3) & 63;
                    int mi2w = (e2 >> 9) & 3;
                    int c = e2 >> 11;
                    int o = mi2w * 16 + (ln2 & 15);
                    int k2 = c * 32 + ((ln2 >> 4) << 3) + el;
                    int tap = k2 >> 8, ch = k2 & 255;
                    wTb2[e2] = (o < 54) ? f2bf(w_off[(o * 256 + ch) * 9 + tap])
                                        : (short)0;
                }
            }
        }
    }

    // ---------------- Grid barrier (all 512 blocks co-resident) ----------
    __threadfence();
    __syncthreads();
    if (t == 0) {
        __hip_atomic_fetch_add(cnt, 1u, __ATOMIC_ACQ_REL, __HIP_MEMORY_SCOPE_AGENT);
        while (__hip_atomic_load(cnt, __ATOMIC_ACQUIRE, __HIP_MEMORY_SCOPE_AGENT)
               < (unsigned)NBLK)
            __builtin_amdgcn_s_sleep(8);
    }
    __syncthreads();

    // ---------------- Geometry (R10) ----------------
    const int bn = ((lin & 7) << 6) | (lin >> 3);   // XCD swizzle
    const int n0 = bn * 32, b = n0 >> 12;
    const unsigned short* xb16 = xT + (size_t)b * HW * 256;
    const char* xbb = (const char*)xb16;
    const int px = t >> 4;          // 0..31
    const int cc = (t >> 2) & 3;    // 32-ch chunk within K=128
    const int q8 = (t & 3) * 8;
    const int ph = ((n0 + px) & 4095) >> 6, pw_ = (n0 + px) & 63;
    const int bsw = ((t & 3) ^ ((px >> 1) & 3)) * 8;
    const int mi2 = wid & 3, ni2 = wid >> 2;        // om tiling 4m x 2n

    // ---------------- Phase 1: om GEMM (A via LDS, 16 KB/iter) ----------
    f32x4 accOm = (f32x4){0.f, 0.f, 0.f, 0.f};
    uint4 bvOm[2];

    auto omload = [&](int gi) -> uint4 {
        const int c = gi * 4 + cc;
        const int tap = c >> 3, c0 = (c & 7) * 32;
        const int hh = ph + tap / 3 - 1, ww = pw_ + tap % 3 - 1;
        uint4 bv = {0u, 0u, 0u, 0u};
        if (hh >= 0 && hh < 64 && ww >= 0 && ww < 64)
            bv = *(const uint4*)(xb16 + (size_t)(hh * 64 + ww) * 256 + c0 + q8);
        return bv;
    };
    auto stageOmA = [&](int gi, int buf) {
#pragma unroll
        for (int r = 0; r < 2; ++r) {
            const int f = 2 * wid + r;             // frag 0..15
            const int cc3 = f >> 2, mi3 = f & 3;
            glds16(wTb2 + (size_t)(gi * 4 + cc3) * 2048 + mi3 * 512 + lane * 8,
                   &AsOm[buf][f * 512 + lane * 8]);
        }
    };

    stageOmA(0, 0);
    bvOm[0] = omload(0);
    *(uint4*)&Bs[0][cc][px * 32 + bsw] = bvOm[0];
    bvOm[1] = omload(1);

#pragma unroll 2
    for (int gi = 0; gi < 18; ++gi) {
        const int p = gi & 1;
        __syncthreads();
        if (gi < 17) {
            stageOmA(gi + 1, 1 - p);
            *(uint4*)&Bs[1 - p][cc][px * 32 + bsw] = bvOm[(gi + 1) & 1];
        }
        if (gi + 2 < 18) bvOm[gi & 1] = omload(gi + 2);
        __builtin_amdgcn_sched_barrier(0);
#pragma unroll
        for (int q = 0; q < 4; ++q) {
            const int row = ni2 * 16 + l16;
            bf16x8 aq = *(const bf16x8*)&AsOm[p][(q * 4 + mi2) * 512 + lane * 8];
            bf16x8 bq = *(const bf16x8*)&Bs[p][q][row * 32 + (quad ^ ((row >> 1) & 3)) * 8];
            accOm = __builtin_amdgcn_mfma_f32_16x16x32_bf16(aq, bq, accOm, 0, 0, 0);
        }
    }
    __syncthreads();
    {
        const int mrow = mi2 * 16 + (lane >> 4) * 4;
        const int pcol = ni2 * 16 + l16;
#pragma unroll
        for (int rr = 0; rr < 4; ++rr)
            omS[mrow + rr][pcol] = accOm[rr];
    }
    __syncthreads();

    // ---------------- Phase 2: plan ----------------
    for (int s = wid; s < 18; s += 8) {
        if (lane < 32) {
            const int nn = n0 + lane;
            const int dg = s >= 9 ? 1 : 0, tap = s - dg * 9;
            const int hh = (nn >> 6) & 63, ww2 = nn & 63;
            const int cdy = dg * 18 + tap, cdx = cdy + 9, cms = 36 + dg * 9 + tap;
            float dy = b_off[cdy] + omS[cdy][lane];
            float dx = b_off[cdx] + omS[cdx][lane];
            float ms = b_off[cms] + omS[cms][lane];
            ms = 1.f / (1.f + __expf(-ms));
            float py = dy + (float)(hh + tap / 3 - 1);
            float qx = dx + (float)(ww2 + tap % 3 - 1);
            float y0f = floorf(py), x0f = floorf(qx);
            float wy1 = py - y0f, wx1 = qx - x0f;
            float wy0 = 1.f - wy1, wx0 = 1.f - wx1;
            int y0 = (int)y0f, x0 = (int)x0f;
            int y1 = y0 + 1, x1 = x0 + 1;
            bool vy0 = (y0 >= 0) & (y0 < 64), vy1 = (y1 >= 0) & (y1 < 64);
            bool vx0 = (x0 >= 0) & (x0 < 64), vx1 = (x1 >= 0) & (x1 < 64);
            int cy0 = min(max(y0, 0), 63), cy1 = min(max(y1, 0), 63);
            int cx0 = min(max(x0, 0), 63), cx1 = min(max(x1, 0), 63);
            float4 wv;
            wv.x = (vy0 && vx0) ? wy0 * wx0 * ms : 0.f;
            wv.y = (vy0 && vx1) ? wy0 * wx1 * ms : 0.f;
            wv.z = (vy1 && vx0) ? wy1 * wx0 * ms : 0.f;
            wv.w = (vy1 && vx1) ? wy1 * wx1 * ms : 0.f;
            int4 iv = make_int4((cy0 * 64 + cx0) << 9, (cy0 * 64 + cx1) << 9,
                                (cy1 * 64 + cx0) << 9, (cy1 * 64 + cx1) << 9);
            PlnW[s][lane] = wv;
            PlnI[s][lane] = iv;
        }
    }
    __syncthreads();

    // ---------------- Phase 3: main fused loop (R10 unchanged) ----------
    const int wr = wid;
    const short* Aw = a2r + (size_t)(wr * 2) * 512 + lane * 8;

    f32x4 acc[2][2];
#pragma unroll
    for (int i = 0; i < 2; ++i)
#pragma unroll
        for (int j = 0; j < 2; ++j) acc[i][j] = (f32x4){0.f, 0.f, 0.f, 0.f};

    float4 pw[2];
    int4 pi[2];
    uint4 g[4];
    uint4 ar[8];

    auto pwload = [&](int S) { pw[S & 1] = PlnW[S][px]; };
    auto piload = [&](int S) { pi[S & 1] = PlnI[S][px]; };
    auto gather = [&](int j) {
        const int cb = ((j >= 9 ? 128 : 0) + cc * 32 + q8) * 2;
        const int4 i4 = pi[j & 1];
        g[0] = *(const uint4*)(xbb + i4.x + cb);
        g[1] = *(const uint4*)(xbb + i4.y + cb);
        g[2] = *(const uint4*)(xbb + i4.z + cb);
        g[3] = *(const uint4*)(xbb + i4.w + cb);
    };
    auto aload = [&](int j) {
#pragma unroll
        for (int ss = 0; ss < 4; ++ss)
#pragma unroll
            for (int mi = 0; mi < 2; ++mi)
                ar[ss * 2 + mi] =
                    *(const uint4*)(Aw + (size_t)(j * 4 + ss) * 8192 + mi * 512);
    };
    auto packwrite = [&](int j, int buf) {
        const float4 w4 = pw[j & 1];
        float a0 = w4.x * blo(g[0].x) + w4.y * blo(g[1].x) + w4.z * blo(g[2].x) + w4.w * blo(g[3].x);
        float a1 = w4.x * bhi(g[0].x) + w4.y * bhi(g[1].x) + w4.z * bhi(g[2].x) + w4.w * bhi(g[3].x);
        float a2v = w4.x * blo(g[0].y) + w4.y * blo(g[1].y) + w4.z * blo(g[2].y) + w4.w * blo(g[3].y);
        float a3 = w4.x * bhi(g[0].y) + w4.y * bhi(g[1].y) + w4.z * bhi(g[2].y) + w4.w * bhi(g[3].y);
        float a4 = w4.x * blo(g[0].z) + w4.y * blo(g[1].z) + w4.z * blo(g[2].z) + w4.w * blo(g[3].z);
        float a5 = w4.x * bhi(g[0].z) + w4.y * bhi(g[1].z) + w4.z * bhi(g[2].z) + w4.w * bhi(g[3].z);
        float a6 = w4.x * blo(g[0].w) + w4.y * blo(g[1].w) + w4.z * blo(g[2].w) + w4.w * blo(g[3].w);
        float a7 = w4.x * bhi(g[0].w) + w4.y * bhi(g[1].w) + w4.z * bhi(g[2].w) + w4.w * bhi(g[3].w);
        uint4 o;
        o.x = cvtpk(a0, a1); o.y = cvtpk(a2v, a3);
        o.z = cvtpk(a4, a5); o.w = cvtpk(a6, a7);
        *(uint4*)&Bs[buf][cc][px * 32 + bsw] = o;
    };
    auto mfmaPhase = [&](int p) {
#pragma unroll
        for (int ss = 0; ss < 4; ++ss) {
            bf16x8 bfr[2];
#pragma unroll
            for (int ni = 0; ni < 2; ++ni) {
                const int row = ni * 16 + l16;
                bfr[ni] = *(const bf16x8*)&Bs[p][ss][row * 32 + (quad ^ ((row >> 1) & 3)) * 8];
            }
#pragma unroll
            for (int mi = 0; mi < 2; ++mi) {
                bf16x8 af = *(const bf16x8*)&ar[ss * 2 + mi];
#pragma unroll
                for (int ni = 0; ni < 2; ++ni)
                    acc[mi][ni] = __builtin_amdgcn_mfma_f32_16x16x32_bf16(
                        af, bfr[ni], acc[mi][ni], 0, 0, 0);
            }
        }
    };

    pwload(0);
    piload(0);
    gather(0);
    aload(0);
    packwrite(0, 0);
    pwload(1);
    piload(1);

#pragma unroll 2
    for (int i = 0; i < 18; ++i) {
        const int p = i & 1;
        __syncthreads();
        if (i + 1 < 18) gather(i + 1);
        if (i + 2 < 18) { pwload(i + 2); piload(i + 2); }
        __builtin_amdgcn_sched_barrier(0);
        mfmaPhase(p);
        if (i + 1 < 18) aload(i + 1);
        if (i + 1 < 18) packwrite(i + 1, 1 - p);
    }

    const int m0 = wr * 32;
#pragma unroll
    for (int mi = 0; mi < 2; ++mi)
#pragma unroll
        for (int ni = 0; ni < 2; ++ni) {
            int nn = n0 + ni * 16 + l16;
            int bidx = nn >> 12, hw = nn & 4095;
            float* op = out + (size_t)bidx * 256 * 4096 + hw;
#pragma unroll
            for (int r = 0; r < 4; ++r) {
                int m = m0 + mi * 16 + quad * 4 + r;
                op[(size_t)m * 4096] = acc[mi][ni][r] + bias[m];
            }
        }
}

// ---------------------------------------------------------------------------
extern "C" void kernel_launch(void* const* d_in, const int* in_sizes, int n_in,
                              void* d_out, int out_size, void* d_ws, size_t ws_size,
                              hipStream_t stream)
{
    const float* x      = (const float*)d_in[0];
    const float* w_off  = (const float*)d_in[1];
    const float* b_off  = (const float*)d_in[2];
    const float* weight = (const float*)d_in[3];
    const float* bias   = (const float*)d_in[4];
    float* out = (float*)d_out;
    char* ws = (char*)d_ws;

    // ws layout:
    unsigned short* xT   = (unsigned short*)(ws);           //  8,388,608
    short*          a2r  = (short*)(ws + 8388608);          //  1,179,648
    short*          wTb2 = (short*)(ws + 9568256);          //    294,912
    unsigned int*   cnt  = (unsigned int*)(ws + 10485760);  //          4

    hipMemsetAsync(cnt, 0, 4, stream);
    hipLaunchKernelGGL(k_all, dim3(NBLK), dim3(512), 0, stream,
                       x, weight, w_off, b_off, bias, xT, a2r, wTb2, cnt, out);
}

// Round 12
// 127.508 us; speedup vs baseline: 1.8087x; 1.8087x over previous
//
#include <hip/hip_runtime.h>
#include <cstdint>

#define HW 4096

typedef __attribute__((ext_vector_type(8))) short bf16x8;
typedef __attribute__((ext_vector_type(4))) float f32x4;

__device__ __forceinline__ short f2bf(float f) {
    union { float f; uint32_t u; } v; v.f = f;
    uint32_t u = v.u;
    uint32_t r = (u + 0x7FFFu + ((u >> 16) & 1u)) >> 16;
    return (short)(r & 0xFFFFu);
}
__device__ __forceinline__ uint32_t cvtpk(float lo, float hi) {
    uint32_t r;
    asm("v_cvt_pk_bf16_f32 %0, %1, %2" : "=v"(r) : "v"(lo), "v"(hi));
    return r;
}
__device__ __forceinline__ float blo(uint32_t u) { return __uint_as_float(u << 16); }
__device__ __forceinline__ float bhi(uint32_t u) { return __uint_as_float(u & 0xFFFF0000u); }
__device__ __forceinline__ void glds16(const void* g, void* l) {
    __builtin_amdgcn_global_load_lds(
        (const __attribute__((address_space(1))) void*)g,
        (__attribute__((address_space(3))) void*)l, 16, 0, 0);
}

// ---------------------------------------------------------------------------
// Kernel 1 (k_pre): all preprocessing in one launch (R10 unchanged).
// blocks 0..1023  : transpose x[b][c][hw] fp32 -> xT[b][hw][c] bf16
// blocks 1024..   : weight conversions (a2r fragment-contiguous + wTb2)
// ---------------------------------------------------------------------------
__global__ __launch_bounds__(256) void k_pre(
    const float* __restrict__ x, const float* __restrict__ weight,
    const float* __restrict__ w_off, unsigned short* __restrict__ xT,
    short* __restrict__ a2r, short* __restrict__ wTb2)
{
    const int bid = blockIdx.x;
    if (bid < 1024) {
        __shared__ unsigned short s[64][65];
        const int t = threadIdx.x, lane = t & 63, grp = t >> 6;
        const int hw0 = (bid & 63) * 64, c0 = ((bid >> 6) & 3) * 64, b = bid >> 8;
#pragma unroll
        for (int j = 0; j < 16; ++j) {
            int cc = grp * 16 + j;
            float v = x[((size_t)(b * 256 + c0 + cc)) * HW + hw0 + lane];
            s[cc][lane] = (unsigned short)f2bf(v);
        }
        __syncthreads();
#pragma unroll
        for (int j = 0; j < 16; ++j) {
            int hw2 = grp * 16 + j;
            xT[((size_t)b * HW + hw0 + hw2) * 256 + c0 + lane] = s[lane][hw2];
        }
    } else {
        int e = (bid - 1024) * 256 + threadIdx.x;   // 0..737279
        if (e < 589824) {
            int el = e & 7;
            int lane = (e >> 3) & 63;
            int rg = (e >> 9) & 15;
            int ss = (e >> 13) & 3;
            int j = e >> 15;                        // 0..17
            int o = rg * 16 + (lane & 15);
            int cch = ss * 32 + (lane >> 4) * 8 + el;
            int dg = j / 9, tap = j - dg * 9;
            a2r[e] = f2bf(weight[o * 2304 + (dg * 128 + cch) * 9 + tap]);
        } else {
            int e2 = e - 589824;                    // 0..147455
            int el = e2 & 7;
            int lane = (e2 >> 3) & 63;
            int mi2 = (e2 >> 9) & 3;
            int c = e2 >> 11;                       // 0..71
            int o = mi2 * 16 + (lane & 15);
            int k = c * 32 + ((lane >> 4) << 3) + el;
            int tap = k >> 8, ch = k & 255;
            wTb2[e2] = (o < 54) ? f2bf(w_off[(o * 256 + ch) * 9 + tap]) : (short)0;
        }
    }
}

// ---------------------------------------------------------------------------
// Kernel 2 (k_fused): om-GEMM + plan + sampling + deformable GEMM (R10)
// with ONE change: om-phase A comes via glds16 LDS double-buffer (AsOm,
// 16 KB/buf, k_omgemm's proven pattern) instead of 4x-redundant register
// loads — halves om L2 A-traffic and removes 8 vmem issues/wave/iter.
// LDS: Bs 16 + AsOm 32 + omS 8 + Pln 18 = 74 KB -> still 2 blocks/CU.
// NO grid barrier / agent fences (R11 lesson: they destroy L2 residency).
// ---------------------------------------------------------------------------
__global__ __launch_bounds__(512, 4) void k_fused(
    const short* __restrict__ A2r, const short* __restrict__ wTb2,
    const unsigned short* __restrict__ xT, const float* __restrict__ b_off,
    const float* __restrict__ bias, float* __restrict__ out)
{
    __shared__ short Bs[2][4][32 * 32];    // 16 KB (om B staging + main B)
    __shared__ short AsOm[2][8192];        // 32 KB (om A dbuf)
    __shared__ float omS[64][32];          //  8 KB
    __shared__ float4 PlnW[18][32];        //  9 KB
    __shared__ int4   PlnI[18][32];        //  9 KB
    const int t = threadIdx.x;
    const int wid = __builtin_amdgcn_readfirstlane(t >> 6);  // 0..7
    const int lane = t & 63;
    const int quad = lane >> 4, l16 = lane & 15;

    // XCD swizzle: 512 blocks, 8 XCDs, 64 contiguous bn per XCD.
    const int lin = blockIdx.x;
    const int bn = ((lin & 7) << 6) | (lin >> 3);

    const int n0 = bn * 32, b = n0 >> 12;
    const unsigned short* xb16 = xT + (size_t)b * HW * 256;
    const char* xbb = (const char*)xb16;
    const int px = t >> 4;          // 0..31
    const int cc = (t >> 2) & 3;    // 32-ch chunk within K=128
    const int q8 = (t & 3) * 8;     // 8-ch granule within chunk
    const int ph = ((n0 + px) & 4095) >> 6, pw_ = (n0 + px) & 63;
    const int bsw = ((t & 3) ^ ((px >> 1) & 3)) * 8;
    const int mi2 = wid & 3, ni2 = wid >> 2;        // om tiling 4m x 2n

    // ---------------- Phase 1: om GEMM (A via LDS, 16 KB/iter) ----------
    f32x4 accOm = (f32x4){0.f, 0.f, 0.f, 0.f};
    uint4 bvOm[2];

    auto omload = [&](int gi) -> uint4 {
        const int c = gi * 4 + cc;
        const int tap = c >> 3, c0 = (c & 7) * 32;
        const int hh = ph + tap / 3 - 1, ww = pw_ + tap % 3 - 1;
        uint4 bv = {0u, 0u, 0u, 0u};
        if (hh >= 0 && hh < 64 && ww >= 0 && ww < 64)
            bv = *(const uint4*)(xb16 + (size_t)(hh * 64 + ww) * 256 + c0 + q8);
        return bv;
    };
    auto stageOmA = [&](int gi, int buf) {
#pragma unroll
        for (int r = 0; r < 2; ++r) {
            const int f = 2 * wid + r;             // frag 0..15
            const int cc3 = f >> 2, mi3 = f & 3;
            glds16(wTb2 + (size_t)(gi * 4 + cc3) * 2048 + mi3 * 512 + lane * 8,
                   &AsOm[buf][f * 512 + lane * 8]);
        }
    };

    stageOmA(0, 0);
    bvOm[0] = omload(0);
    *(uint4*)&Bs[0][cc][px * 32 + bsw] = bvOm[0];
    bvOm[1] = omload(1);

#pragma unroll 2
    for (int gi = 0; gi < 18; ++gi) {
        const int p = gi & 1;
        __syncthreads();
        if (gi < 17) {
            stageOmA(gi + 1, 1 - p);
            *(uint4*)&Bs[1 - p][cc][px * 32 + bsw] = bvOm[(gi + 1) & 1];
        }
        if (gi + 2 < 18) bvOm[gi & 1] = omload(gi + 2);
        __builtin_amdgcn_sched_barrier(0);
#pragma unroll
        for (int q = 0; q < 4; ++q) {
            const int row = ni2 * 16 + l16;
            bf16x8 aq = *(const bf16x8*)&AsOm[p][(q * 4 + mi2) * 512 + lane * 8];
            bf16x8 bq = *(const bf16x8*)&Bs[p][q][row * 32 + (quad ^ ((row >> 1) & 3)) * 8];
            accOm = __builtin_amdgcn_mfma_f32_16x16x32_bf16(aq, bq, accOm, 0, 0, 0);
        }
    }
    __syncthreads();
    {   // om C/D: col = lane&15 (px within n-tile), row = (lane>>4)*4 + r
        const int mrow = mi2 * 16 + (lane >> 4) * 4;
        const int pcol = ni2 * 16 + l16;
#pragma unroll
        for (int rr = 0; rr < 4; ++rr)
            omS[mrow + rr][pcol] = accOm[rr];
    }
    __syncthreads();

    // ---------------- Phase 2: plan ----------------
    for (int s = wid; s < 18; s += 8) {
        if (lane < 32) {
            const int nn = n0 + lane;
            const int dg = s >= 9 ? 1 : 0, tap = s - dg * 9;
            const int hh = (nn >> 6) & 63, ww2 = nn & 63;
            const int cdy = dg * 18 + tap, cdx = cdy + 9, cms = 36 + dg * 9 + tap;
            float dy = b_off[cdy] + omS[cdy][lane];
            float dx = b_off[cdx] + omS[cdx][lane];
            float ms = b_off[cms] + omS[cms][lane];
            ms = 1.f / (1.f + __expf(-ms));
            float py = dy + (float)(hh + tap / 3 - 1);
            float qx = dx + (float)(ww2 + tap % 3 - 1);
            float y0f = floorf(py), x0f = floorf(qx);
            float wy1 = py - y0f, wx1 = qx - x0f;
            float wy0 = 1.f - wy1, wx0 = 1.f - wx1;
            int y0 = (int)y0f, x0 = (int)x0f;
            int y1 = y0 + 1, x1 = x0 + 1;
            bool vy0 = (y0 >= 0) & (y0 < 64), vy1 = (y1 >= 0) & (y1 < 64);
            bool vx0 = (x0 >= 0) & (x0 < 64), vx1 = (x1 >= 0) & (x1 < 64);
            int cy0 = min(max(y0, 0), 63), cy1 = min(max(y1, 0), 63);
            int cx0 = min(max(x0, 0), 63), cx1 = min(max(x1, 0), 63);
            float4 wv;
            wv.x = (vy0 && vx0) ? wy0 * wx0 * ms : 0.f;
            wv.y = (vy0 && vx1) ? wy0 * wx1 * ms : 0.f;
            wv.z = (vy1 && vx0) ? wy1 * wx0 * ms : 0.f;
            wv.w = (vy1 && vx1) ? wy1 * wx1 * ms : 0.f;
            int4 iv = make_int4((cy0 * 64 + cx0) << 9, (cy0 * 64 + cx1) << 9,
                                (cy1 * 64 + cx0) << 9, (cy1 * 64 + cx1) << 9);
            PlnW[s][lane] = wv;
            PlnI[s][lane] = iv;
        }
    }
    __syncthreads();

    // ---------------- Phase 3: main fused loop (R10 unchanged) ----------
    const int wr = wid;
    const short* Aw = A2r + (size_t)(wr * 2) * 512 + lane * 8;

    f32x4 acc[2][2];
#pragma unroll
    for (int i = 0; i < 2; ++i)
#pragma unroll
        for (int j = 0; j < 2; ++j) acc[i][j] = (f32x4){0.f, 0.f, 0.f, 0.f};

    float4 pw[2];
    int4 pi[2];
    uint4 g[4];
    uint4 ar[8];

    auto pwload = [&](int S) { pw[S & 1] = PlnW[S][px]; };
    auto piload = [&](int S) { pi[S & 1] = PlnI[S][px]; };
    auto gather = [&](int j) {
        const int cb = ((j >= 9 ? 128 : 0) + cc * 32 + q8) * 2;
        const int4 i4 = pi[j & 1];
        g[0] = *(const uint4*)(xbb + i4.x + cb);
        g[1] = *(const uint4*)(xbb + i4.y + cb);
        g[2] = *(const uint4*)(xbb + i4.z + cb);
        g[3] = *(const uint4*)(xbb + i4.w + cb);
    };
    auto aload = [&](int j) {
#pragma unroll
        for (int ss = 0; ss < 4; ++ss)
#pragma unroll
            for (int mi = 0; mi < 2; ++mi)
                ar[ss * 2 + mi] =
                    *(const uint4*)(Aw + (size_t)(j * 4 + ss) * 8192 + mi * 512);
    };
    auto packwrite = [&](int j, int buf) {
        const float4 w4 = pw[j & 1];
        float a0 = w4.x * blo(g[0].x) + w4.y * blo(g[1].x) + w4.z * blo(g[2].x) + w4.w * blo(g[3].x);
        float a1 = w4.x * bhi(g[0].x) + w4.y * bhi(g[1].x) + w4.z * bhi(g[2].x) + w4.w * bhi(g[3].x);
        float a2v = w4.x * blo(g[0].y) + w4.y * blo(g[1].y) + w4.z * blo(g[2].y) + w4.w * blo(g[3].y);
        float a3 = w4.x * bhi(g[0].y) + w4.y * bhi(g[1].y) + w4.z * bhi(g[2].y) + w4.w * bhi(g[3].y);
        float a4 = w4.x * blo(g[0].z) + w4.y * blo(g[1].z) + w4.z * blo(g[2].z) + w4.w * blo(g[3].z);
        float a5 = w4.x * bhi(g[0].z) + w4.y * bhi(g[1].z) + w4.z * bhi(g[2].z) + w4.w * bhi(g[3].z);
        float a6 = w4.x * blo(g[0].w) + w4.y * blo(g[1].w) + w4.z * blo(g[2].w) + w4.w * blo(g[3].w);
        float a7 = w4.x * bhi(g[0].w) + w4.y * bhi(g[1].w) + w4.z * bhi(g[2].w) + w4.w * bhi(g[3].w);
        uint4 o;
        o.x = cvtpk(a0, a1); o.y = cvtpk(a2v, a3);
        o.z = cvtpk(a4, a5); o.w = cvtpk(a6, a7);
        *(uint4*)&Bs[buf][cc][px * 32 + bsw] = o;
    };
    auto mfmaPhase = [&](int p) {
#pragma unroll
        for (int ss = 0; ss < 4; ++ss) {
            bf16x8 bfr[2];
#pragma unroll
            for (int ni = 0; ni < 2; ++ni) {
                const int row = ni * 16 + l16;
                bfr[ni] = *(const bf16x8*)&Bs[p][ss][row * 32 + (quad ^ ((row >> 1) & 3)) * 8];
            }
#pragma unroll
            for (int mi = 0; mi < 2; ++mi) {
                bf16x8 af = *(const bf16x8*)&ar[ss * 2 + mi];
#pragma unroll
                for (int ni = 0; ni < 2; ++ni)
                    acc[mi][ni] = __builtin_amdgcn_mfma_f32_16x16x32_bf16(
                        af, bfr[ni], acc[mi][ni], 0, 0, 0);
            }
        }
    };

    pwload(0);
    piload(0);
    gather(0);
    aload(0);
    packwrite(0, 0);
    pwload(1);
    piload(1);

#pragma unroll 2
    for (int i = 0; i < 18; ++i) {
        const int p = i & 1;
        __syncthreads();
        if (i + 1 < 18) gather(i + 1);
        if (i + 2 < 18) { pwload(i + 2); piload(i + 2); }
        __builtin_amdgcn_sched_barrier(0);
        mfmaPhase(p);
        if (i + 1 < 18) aload(i + 1);
        if (i + 1 < 18) packwrite(i + 1, 1 - p);
    }

    const int m0 = wr * 32;
#pragma unroll
    for (int mi = 0; mi < 2; ++mi)
#pragma unroll
        for (int ni = 0; ni < 2; ++ni) {
            int nn = n0 + ni * 16 + l16;
            int bidx = nn >> 12, hw = nn & 4095;
            float* op = out + (size_t)bidx * 256 * 4096 + hw;
#pragma unroll
            for (int r = 0; r < 4; ++r) {
                int m = m0 + mi * 16 + quad * 4 + r;
                op[(size_t)m * 4096] = acc[mi][ni][r] + bias[m];
            }
        }
}

// ---------------------------------------------------------------------------
extern "C" void kernel_launch(void* const* d_in, const int* in_sizes, int n_in,
                              void* d_out, int out_size, void* d_ws, size_t ws_size,
                              hipStream_t stream)
{
    const float* x      = (const float*)d_in[0];
    const float* w_off  = (const float*)d_in[1];
    const float* b_off  = (const float*)d_in[2];
    const float* weight = (const float*)d_in[3];
    const float* bias   = (const float*)d_in[4];
    float* out = (float*)d_out;
    char* ws = (char*)d_ws;

    // ws layout (9,863,168 B used):
    unsigned short* xT   = (unsigned short*)(ws);           //  8,388,608
    short*          a2r  = (short*)(ws + 8388608);          //  1,179,648
    short*          wTb2 = (short*)(ws + 9568256);          //    294,912

    hipLaunchKernelGGL(k_pre, dim3(3904), dim3(256), 0, stream,
                       x, weight, w_off, xT, a2r, wTb2);
    hipLaunchKernelGGL(k_fused, dim3(512), dim3(512), 0, stream,
                       a2r, wTb2, xT, b_off, bias, out);
}

// Round 13
// 123.102 us; speedup vs baseline: 1.8734x; 1.0358x over previous
//
#include <hip/hip_runtime.h>
#include <cstdint>

#define HW 4096

typedef __attribute__((ext_vector_type(8))) short bf16x8;
typedef __attribute__((ext_vector_type(4))) float f32x4;

__device__ __forceinline__ short f2bf(float f) {
    union { float f; uint32_t u; } v; v.f = f;
    uint32_t u = v.u;
    uint32_t r = (u + 0x7FFFu + ((u >> 16) & 1u)) >> 16;
    return (short)(r & 0xFFFFu);
}
__device__ __forceinline__ uint32_t cvtpk(float lo, float hi) {
    uint32_t r;
    asm("v_cvt_pk_bf16_f32 %0, %1, %2" : "=v"(r) : "v"(lo), "v"(hi));
    return r;
}
__device__ __forceinline__ float blo(uint32_t u) { return __uint_as_float(u << 16); }
__device__ __forceinline__ float bhi(uint32_t u) { return __uint_as_float(u & 0xFFFF0000u); }

// ---------------------------------------------------------------------------
// Kernel 1 (k_pre): all preprocessing in one launch (R10 unchanged).
// blocks 0..1023  : transpose x[b][c][hw] fp32 -> xT[b][hw][c] bf16
// blocks 1024..   : weight conversions (a2r fragment-contiguous + wTb2)
// ---------------------------------------------------------------------------
__global__ __launch_bounds__(256) void k_pre(
    const float* __restrict__ x, const float* __restrict__ weight,
    const float* __restrict__ w_off, unsigned short* __restrict__ xT,
    short* __restrict__ a2r, short* __restrict__ wTb2)
{
    const int bid = blockIdx.x;
    if (bid < 1024) {
        __shared__ unsigned short s[64][65];
        const int t = threadIdx.x, lane = t & 63, grp = t >> 6;
        const int hw0 = (bid & 63) * 64, c0 = ((bid >> 6) & 3) * 64, b = bid >> 8;
#pragma unroll
        for (int j = 0; j < 16; ++j) {
            int cc = grp * 16 + j;
            float v = x[((size_t)(b * 256 + c0 + cc)) * HW + hw0 + lane];
            s[cc][lane] = (unsigned short)f2bf(v);
        }
        __syncthreads();
#pragma unroll
        for (int j = 0; j < 16; ++j) {
            int hw2 = grp * 16 + j;
            xT[((size_t)b * HW + hw0 + hw2) * 256 + c0 + lane] = s[lane][hw2];
        }
    } else {
        int e = (bid - 1024) * 256 + threadIdx.x;   // 0..737279
        if (e < 589824) {
            int el = e & 7;
            int lane = (e >> 3) & 63;
            int rg = (e >> 9) & 15;
            int ss = (e >> 13) & 3;
            int j = e >> 15;                        // 0..17
            int o = rg * 16 + (lane & 15);
            int cch = ss * 32 + (lane >> 4) * 8 + el;
            int dg = j / 9, tap = j - dg * 9;
            a2r[e] = f2bf(weight[o * 2304 + (dg * 128 + cch) * 9 + tap]);
        } else {
            int e2 = e - 589824;                    // 0..147455
            int el = e2 & 7;
            int lane = (e2 >> 3) & 63;
            int mi2 = (e2 >> 9) & 3;
            int c = e2 >> 11;                       // 0..71
            int o = mi2 * 16 + (lane & 15);
            int k = c * 32 + ((lane >> 4) << 3) + el;
            int tap = k >> 8, ch = k & 255;
            wTb2[e2] = (o < 54) ? f2bf(w_off[(o * 256 + ch) * 9 + tap]) : (short)0;
        }
    }
}

// ---------------------------------------------------------------------------
// Kernel 2 (k_fused): om-GEMM + plan + sampling + deformable GEMM.
// R10 base with ONE change: om phase DEEPENED to K=256/iter — 9 iterations
// (8 chunks, 8 MFMA/wave each) instead of 18. Same total MFMA and bytes;
// HALF the barrier/drain quanta (the om phase is per-iteration-overhead
// bound: R12 proved traffic-neutral, 4 MFMA vs ~1330 cyc/iter).
// Bs widened to [2][8] (32 KB; main loop uses chunks 0..3 of each buffer).
// arOm[8] single-buffered, loaded after its MFMA consumption (R10
// discipline, rule-#20 clean: no parity-indexed register arrays).
// LDS: Bs 32 + omS 8 + Pln 18 = 58 KB -> 2 blocks/CU (116 KB).
// NO grid barrier / agent fences (R11), NO AsOm staging (R12 null).
// ---------------------------------------------------------------------------
__global__ __launch_bounds__(512, 4) void k_fused(
    const short* __restrict__ A2r, const short* __restrict__ wTb2,
    const unsigned short* __restrict__ xT, const float* __restrict__ b_off,
    const float* __restrict__ bias, float* __restrict__ out)
{
    __shared__ short Bs[2][8][32 * 32];    // 32 KB (om: 8 chunks; main: 0..3)
    __shared__ float omS[64][32];          //  8 KB
    __shared__ float4 PlnW[18][32];        //  9 KB
    __shared__ int4   PlnI[18][32];        //  9 KB
    const int t = threadIdx.x;
    const int wid = __builtin_amdgcn_readfirstlane(t >> 6);  // 0..7
    const int lane = t & 63;
    const int quad = lane >> 4, l16 = lane & 15;

    // XCD swizzle: 512 blocks, 8 XCDs, 64 contiguous bn per XCD.
    const int lin = blockIdx.x;
    const int bn = ((lin & 7) << 6) | (lin >> 3);

    const int n0 = bn * 32, b = n0 >> 12;
    const unsigned short* xb16 = xT + (size_t)b * HW * 256;
    const char* xbb = (const char*)xb16;
    const int px = t >> 4;          // 0..31
    const int cc = (t >> 2) & 3;    // 32-ch chunk slot
    const int q8 = (t & 3) * 8;     // 8-ch granule within chunk
    const int ph = ((n0 + px) & 4095) >> 6, pw_ = (n0 + px) & 63;
    const int bsw = ((t & 3) ^ ((px >> 1) & 3)) * 8;
    const int mi2 = wid & 3, ni2 = wid >> 2;        // om tiling 4m x 2n

    // ---------------- Phase 1: om GEMM (K=256/iter, 9 iters) ----------
    f32x4 accOm = (f32x4){0.f, 0.f, 0.f, 0.f};
    uint4 arOm[8];
    uint4 gv0, gv1;

    auto omload = [&](int c) -> uint4 {     // c = global chunk id 0..71
        const int tap = c >> 3, c0 = (c & 7) * 32;
        const int hh = ph + tap / 3 - 1, ww = pw_ + tap % 3 - 1;
        uint4 bv = {0u, 0u, 0u, 0u};
        if (hh >= 0 && hh < 64 && ww >= 0 && ww < 64)
            bv = *(const uint4*)(xb16 + (size_t)(hh * 64 + ww) * 256 + c0 + q8);
        return bv;
    };
    auto aloadOm = [&](int gi) {
#pragma unroll
        for (int q = 0; q < 8; ++q)
            arOm[q] = *(const uint4*)(wTb2 + (size_t)(gi * 8 + q) * 2048
                                      + mi2 * 512 + lane * 8);
    };

    aloadOm(0);
    gv0 = omload(cc);
    gv1 = omload(cc + 4);
    *(uint4*)&Bs[0][cc][px * 32 + bsw] = gv0;
    *(uint4*)&Bs[0][cc + 4][px * 32 + bsw] = gv1;

#pragma unroll 1
    for (int gi = 0; gi < 9; ++gi) {
        const int p = gi & 1;
        __syncthreads();
        if (gi + 1 < 9) {
            gv0 = omload((gi + 1) * 8 + cc);
            gv1 = omload((gi + 1) * 8 + cc + 4);
        }
        __builtin_amdgcn_sched_barrier(0);
#pragma unroll
        for (int q = 0; q < 8; ++q) {
            const int row = ni2 * 16 + l16;
            bf16x8 bq = *(const bf16x8*)&Bs[p][q][row * 32 + (quad ^ ((row >> 1) & 3)) * 8];
            accOm = __builtin_amdgcn_mfma_f32_16x16x32_bf16(
                *(const bf16x8*)&arOm[q], bq, accOm, 0, 0, 0);
        }
        if (gi + 1 < 9) {
            *(uint4*)&Bs[1 - p][cc][px * 32 + bsw] = gv0;
            *(uint4*)&Bs[1 - p][cc + 4][px * 32 + bsw] = gv1;
            aloadOm(gi + 1);
        }
    }
    __syncthreads();
    {   // om C/D: col = lane&15 (px within n-tile), row = (lane>>4)*4 + r
        const int mrow = mi2 * 16 + (lane >> 4) * 4;
        const int pcol = ni2 * 16 + l16;
#pragma unroll
        for (int rr = 0; rr < 4; ++rr)
            omS[mrow + rr][pcol] = accOm[rr];
    }
    __syncthreads();

    // ---------------- Phase 2: plan ----------------
    for (int s = wid; s < 18; s += 8) {
        if (lane < 32) {
            const int nn = n0 + lane;
            const int dg = s >= 9 ? 1 : 0, tap = s - dg * 9;
            const int hh = (nn >> 6) & 63, ww2 = nn & 63;
            const int cdy = dg * 18 + tap, cdx = cdy + 9, cms = 36 + dg * 9 + tap;
            float dy = b_off[cdy] + omS[cdy][lane];
            float dx = b_off[cdx] + omS[cdx][lane];
            float ms = b_off[cms] + omS[cms][lane];
            ms = 1.f / (1.f + __expf(-ms));
            float py = dy + (float)(hh + tap / 3 - 1);
            float qx = dx + (float)(ww2 + tap % 3 - 1);
            float y0f = floorf(py), x0f = floorf(qx);
            float wy1 = py - y0f, wx1 = qx - x0f;
            float wy0 = 1.f - wy1, wx0 = 1.f - wx1;
            int y0 = (int)y0f, x0 = (int)x0f;
            int y1 = y0 + 1, x1 = x0 + 1;
            bool vy0 = (y0 >= 0) & (y0 < 64), vy1 = (y1 >= 0) & (y1 < 64);
            bool vx0 = (x0 >= 0) & (x0 < 64), vx1 = (x1 >= 0) & (x1 < 64);
            int cy0 = min(max(y0, 0), 63), cy1 = min(max(y1, 0), 63);
            int cx0 = min(max(x0, 0), 63), cx1 = min(max(x1, 0), 63);
            float4 wv;
            wv.x = (vy0 && vx0) ? wy0 * wx0 * ms : 0.f;
            wv.y = (vy0 && vx1) ? wy0 * wx1 * ms : 0.f;
            wv.z = (vy1 && vx0) ? wy1 * wx0 * ms : 0.f;
            wv.w = (vy1 && vx1) ? wy1 * wx1 * ms : 0.f;
            int4 iv = make_int4((cy0 * 64 + cx0) << 9, (cy0 * 64 + cx1) << 9,
                                (cy1 * 64 + cx0) << 9, (cy1 * 64 + cx1) << 9);
            PlnW[s][lane] = wv;
            PlnI[s][lane] = iv;
        }
    }
    __syncthreads();

    // ---------------- Phase 3: main fused loop (R10 unchanged) ----------
    const int wr = wid;
    const short* Aw = A2r + (size_t)(wr * 2) * 512 + lane * 8;

    f32x4 acc[2][2];
#pragma unroll
    for (int i = 0; i < 2; ++i)
#pragma unroll
        for (int j = 0; j < 2; ++j) acc[i][j] = (f32x4){0.f, 0.f, 0.f, 0.f};

    float4 pw[2];
    int4 pi[2];
    uint4 g[4];
    uint4 ar[8];

    auto pwload = [&](int S) { pw[S & 1] = PlnW[S][px]; };
    auto piload = [&](int S) { pi[S & 1] = PlnI[S][px]; };
    auto gather = [&](int j) {
        const int cb = ((j >= 9 ? 128 : 0) + cc * 32 + q8) * 2;
        const int4 i4 = pi[j & 1];
        g[0] = *(const uint4*)(xbb + i4.x + cb);
        g[1] = *(const uint4*)(xbb + i4.y + cb);
        g[2] = *(const uint4*)(xbb + i4.z + cb);
        g[3] = *(const uint4*)(xbb + i4.w + cb);
    };
    auto aload = [&](int j) {
#pragma unroll
        for (int ss = 0; ss < 4; ++ss)
#pragma unroll
            for (int mi = 0; mi < 2; ++mi)
                ar[ss * 2 + mi] =
                    *(const uint4*)(Aw + (size_t)(j * 4 + ss) * 8192 + mi * 512);
    };
    auto packwrite = [&](int j, int buf) {
        const float4 w4 = pw[j & 1];
        float a0 = w4.x * blo(g[0].x) + w4.y * blo(g[1].x) + w4.z * blo(g[2].x) + w4.w * blo(g[3].x);
        float a1 = w4.x * bhi(g[0].x) + w4.y * bhi(g[1].x) + w4.z * bhi(g[2].x) + w4.w * bhi(g[3].x);
        float a2v = w4.x * blo(g[0].y) + w4.y * blo(g[1].y) + w4.z * blo(g[2].y) + w4.w * blo(g[3].y);
        float a3 = w4.x * bhi(g[0].y) + w4.y * bhi(g[1].y) + w4.z * bhi(g[2].y) + w4.w * bhi(g[3].y);
        float a4 = w4.x * blo(g[0].z) + w4.y * blo(g[1].z) + w4.z * blo(g[2].z) + w4.w * blo(g[3].z);
        float a5 = w4.x * bhi(g[0].z) + w4.y * bhi(g[1].z) + w4.z * bhi(g[2].z) + w4.w * bhi(g[3].z);
        float a6 = w4.x * blo(g[0].w) + w4.y * blo(g[1].w) + w4.z * blo(g[2].w) + w4.w * blo(g[3].w);
        float a7 = w4.x * bhi(g[0].w) + w4.y * bhi(g[1].w) + w4.z * bhi(g[2].w) + w4.w * bhi(g[3].w);
        uint4 o;
        o.x = cvtpk(a0, a1); o.y = cvtpk(a2v, a3);
        o.z = cvtpk(a4, a5); o.w = cvtpk(a6, a7);
        *(uint4*)&Bs[buf][cc][px * 32 + bsw] = o;
    };
    auto mfmaPhase = [&](int p) {
#pragma unroll
        for (int ss = 0; ss < 4; ++ss) {
            bf16x8 bfr[2];
#pragma unroll
            for (int ni = 0; ni < 2; ++ni) {
                const int row = ni * 16 + l16;
                bfr[ni] = *(const bf16x8*)&Bs[p][ss][row * 32 + (quad ^ ((row >> 1) & 3)) * 8];
            }
#pragma unroll
            for (int mi = 0; mi < 2; ++mi) {
                bf16x8 af = *(const bf16x8*)&ar[ss * 2 + mi];
#pragma unroll
                for (int ni = 0; ni < 2; ++ni)
                    acc[mi][ni] = __builtin_amdgcn_mfma_f32_16x16x32_bf16(
                        af, bfr[ni], acc[mi][ni], 0, 0, 0);
            }
        }
    };

    pwload(0);
    piload(0);
    gather(0);
    aload(0);
    packwrite(0, 0);
    pwload(1);
    piload(1);

#pragma unroll 2
    for (int i = 0; i < 18; ++i) {
        const int p = i & 1;
        __syncthreads();
        if (i + 1 < 18) gather(i + 1);
        if (i + 2 < 18) { pwload(i + 2); piload(i + 2); }
        __builtin_amdgcn_sched_barrier(0);
        mfmaPhase(p);
        if (i + 1 < 18) aload(i + 1);
        if (i + 1 < 18) packwrite(i + 1, 1 - p);
    }

    const int m0 = wr * 32;
#pragma unroll
    for (int mi = 0; mi < 2; ++mi)
#pragma unroll
        for (int ni = 0; ni < 2; ++ni) {
            int nn = n0 + ni * 16 + l16;
            int bidx = nn >> 12, hw = nn & 4095;
            float* op = out + (size_t)bidx * 256 * 4096 + hw;
#pragma unroll
            for (int r = 0; r < 4; ++r) {
                int m = m0 + mi * 16 + quad * 4 + r;
                op[(size_t)m * 4096] = acc[mi][ni][r] + bias[m];
            }
        }
}

// ---------------------------------------------------------------------------
extern "C" void kernel_launch(void* const* d_in, const int* in_sizes, int n_in,
                              void* d_out, int out_size, void* d_ws, size_t ws_size,
                              hipStream_t stream)
{
    const float* x      = (const float*)d_in[0];
    const float* w_off  = (const float*)d_in[1];
    const float* b_off  = (const float*)d_in[2];
    const float* weight = (const float*)d_in[3];
    const float* bias   = (const float*)d_in[4];
    float* out = (float*)d_out;
    char* ws = (char*)d_ws;

    // ws layout (9,863,168 B used):
    unsigned short* xT   = (unsigned short*)(ws);           //  8,388,608
    short*          a2r  = (short*)(ws + 8388608);          //  1,179,648
    short*          wTb2 = (short*)(ws + 9568256);          //    294,912

    hipLaunchKernelGGL(k_pre, dim3(3904), dim3(256), 0, stream,
                       x, weight, w_off, xT, a2r, wTb2);
    hipLaunchKernelGGL(k_fused, dim3(512), dim3(512), 0, stream,
                       a2r, wTb2, xT, b_off, bias, out);
}